// Round 1
// 2538.272 us; speedup vs baseline: 1.3703x; 1.3703x over previous
//
#include <hip/hip_runtime.h>
#include <math.h>

#define MR_C     256
#define MR_L     8192
#define MR_DEPTH 12
#define TPB      1024
// each thread owns 2 float4 groups, strided TPB apart (coalesced)

__device__ __forceinline__ float4 f4z() { return make_float4(0.f, 0.f, 0.f, 0.f); }

// One level-step for one float4 group. LEV folds the dilation at compile time.
// res_lo is re-read from LDS (bc[g]) instead of being carried in registers:
// it is identical to what was stored last level, and shedding 8 persistent
// VGPRs is worth one extra ds_read_b128 per group per level.
template<int LEV>
__device__ __forceinline__ float4 level_group(
    int g, float4& acc,
    const float4* __restrict__ bc,
    const float4 F0, const float4 F1, const float wi)
{
    constexpr int d = 1 << LEV;
    const float4 rl = bc[g];
    float4 t1, t2, t3;   // taps at t-d, t-2d, t-3d

    if constexpr (d == 1) {
        float4 p = (g >= 1) ? bc[g - 1] : f4z();
        t1 = make_float4(p.w, rl.x, rl.y, rl.z);
        t2 = make_float4(p.z, p.w, rl.x, rl.y);
        t3 = make_float4(p.y, p.z, p.w, rl.x);
    } else if constexpr (d == 2) {
        float4 p  = (g >= 1) ? bc[g - 1] : f4z();
        float4 p2 = (g >= 2) ? bc[g - 2] : f4z();
        t1 = make_float4(p.z, p.w, rl.x, rl.y);
        t2 = p;
        t3 = make_float4(p2.z, p2.w, p.x, p.y);
    } else {
        constexpr int d4 = d >> 2;   // d % 4 == 0: aligned float4 taps
        t1 = (g >= d4)     ? bc[g - d4]     : f4z();
        t2 = (g >= 2 * d4) ? bc[g - 2 * d4] : f4z();
        t3 = (g >= 3 * d4) ? bc[g - 3 * d4] : f4z();
    }

    // coefficient of x[t - d*j] is h[3-j]:  F.w*x[t] + F.z*x[t-d] + F.y*x[t-2d] + F.x*x[t-3d]
    float4 nl, hi;
    nl.x = F0.w * rl.x + F0.z * t1.x + F0.y * t2.x + F0.x * t3.x;
    nl.y = F0.w * rl.y + F0.z * t1.y + F0.y * t2.y + F0.x * t3.y;
    nl.z = F0.w * rl.z + F0.z * t1.z + F0.y * t2.z + F0.x * t3.z;
    nl.w = F0.w * rl.w + F0.z * t1.w + F0.y * t2.w + F0.x * t3.w;

    hi.x = F1.w * rl.x + F1.z * t1.x + F1.y * t2.x + F1.x * t3.x;
    hi.y = F1.w * rl.y + F1.z * t1.y + F1.y * t2.y + F1.x * t3.y;
    hi.z = F1.w * rl.z + F1.z * t1.z + F1.y * t2.z + F1.x * t3.z;
    hi.w = F1.w * rl.w + F1.z * t1.w + F1.y * t2.w + F1.x * t3.w;

    acc.x += wi * hi.x;
    acc.y += wi * hi.y;
    acc.z += wi * hi.z;
    acc.w += wi * hi.w;

    return nl;
}

// R3 THEORY: counters showed VGPR_Count=64 (the 8-waves/EU cap the compiler's
// occupancy heuristic picks because 64KiB LDS allows 2 blocks/CU) with 12.75 GB
// of HBM traffic/dispatch vs 268 MB ideal => ~30 spill slots/thread round-tripping
// through scratch every level. amdgpu_waves_per_eu(4,4) raises the cap to
// 512/4 = 128 VGPRs and disables the 8-wave heuristic. Occupancy may drop to
// 1 block/CU -- acceptable: spill traffic is 47x the useful traffic.
__attribute__((amdgpu_waves_per_eu(4, 4)))
__global__ __launch_bounds__(TPB) void multires_fused(
    const float* __restrict__ x,
    const float* __restrict__ h0,
    const float* __restrict__ h1,
    const float* __restrict__ w,
    float* __restrict__ out)
{
    __shared__ float4 buf0[MR_L / 4];
    __shared__ float4 buf1[MR_L / 4];

    const int row = blockIdx.x;            // b*C + c
    const int c   = row & (MR_C - 1);
    const int tid = threadIdx.x;

    // block-uniform filter/weight loads (scalar path, L2-cached)
    const float4 F0 = ((const float4*)h0)[c];
    const float4 F1 = ((const float4*)h1)[c];
    const float* __restrict__ wrow = w + c * (MR_DEPTH + 2);
    const float wlast = wrow[MR_DEPTH + 1];

    const float4* __restrict__ xrow = (const float4*)(x + (size_t)row * MR_L);
    const int g0 = tid, g1 = tid + TPB;

    float4 v0 = xrow[g0], v1 = xrow[g1];
    float4 acc0, acc1;
    acc0.x = v0.x * wlast; acc0.y = v0.y * wlast; acc0.z = v0.z * wlast; acc0.w = v0.w * wlast;
    acc1.x = v1.x * wlast; acc1.y = v1.y * wlast; acc1.z = v1.z * wlast; acc1.w = v1.w * wlast;
    buf0[g0] = v0; buf0[g1] = v1;
    __syncthreads();

    const float4* bc = buf0;
    float4*       bn = buf1;

    float4 nl0, nl1;   // current level's res_lo; after DO_LEVEL(11) = final res_lo

#define DO_LEVEL(LEV)                                                          \
    {                                                                          \
        const float wi = wrow[MR_DEPTH - (LEV)];                               \
        nl0 = level_group<LEV>(g0, acc0, bc, F0, F1, wi);                      \
        nl1 = level_group<LEV>(g1, acc1, bc, F0, F1, wi);                      \
        if ((LEV) != MR_DEPTH - 1) {                                           \
            bn[g0] = nl0; bn[g1] = nl1;                                        \
            __syncthreads();                                                   \
        }                                                                      \
        const float4* tswap = bn; bn = (float4*)bc; bc = tswap;                \
    }

    DO_LEVEL(0)  DO_LEVEL(1)  DO_LEVEL(2)  DO_LEVEL(3)
    DO_LEVEL(4)  DO_LEVEL(5)  DO_LEVEL(6)  DO_LEVEL(7)
    DO_LEVEL(8)  DO_LEVEL(9)  DO_LEVEL(10) DO_LEVEL(11)
#undef DO_LEVEL

    // epilogue: y += w[:,0] * res_lo; exact-erf GELU; coalesced float4 store
    float4* __restrict__ orow = (float4*)(out + (size_t)row * MR_L);
    const float w0 = wrow[0];
    const float inv_sqrt2 = 0.70710678118654752f;

    float4 v; float u;
    u = acc0.x + w0 * nl0.x; v.x = 0.5f * u * (1.0f + erff(u * inv_sqrt2));
    u = acc0.y + w0 * nl0.y; v.y = 0.5f * u * (1.0f + erff(u * inv_sqrt2));
    u = acc0.z + w0 * nl0.z; v.z = 0.5f * u * (1.0f + erff(u * inv_sqrt2));
    u = acc0.w + w0 * nl0.w; v.w = 0.5f * u * (1.0f + erff(u * inv_sqrt2));
    orow[g0] = v;
    u = acc1.x + w0 * nl1.x; v.x = 0.5f * u * (1.0f + erff(u * inv_sqrt2));
    u = acc1.y + w0 * nl1.y; v.y = 0.5f * u * (1.0f + erff(u * inv_sqrt2));
    u = acc1.z + w0 * nl1.z; v.z = 0.5f * u * (1.0f + erff(u * inv_sqrt2));
    u = acc1.w + w0 * nl1.w; v.w = 0.5f * u * (1.0f + erff(u * inv_sqrt2));
    orow[g1] = v;
}

extern "C" void kernel_launch(void* const* d_in, const int* in_sizes, int n_in,
                              void* d_out, int out_size, void* d_ws, size_t ws_size,
                              hipStream_t stream) {
    const float* x  = (const float*)d_in[0];
    const float* h0 = (const float*)d_in[1];
    const float* h1 = (const float*)d_in[2];
    const float* w  = (const float*)d_in[3];
    float* o        = (float*)d_out;

    const int rows = in_sizes[0] / MR_L;   // B*C = 4096
    multires_fused<<<rows, TPB, 0, stream>>>(x, h0, h1, w, o);
}